// Round 1
// baseline (1543.734 us; speedup 1.0000x reference)
//
#include <hip/hip_runtime.h>
#include <hip/hip_bf16.h>
#include <cstdint>

// EquivariantMPLayer: out = embed@W_res + relu(embed@Wu1 + aggr@Wu2 + b_upd)
//   aggr[c] = sum_{e: col[e]==c} relu(embed[row]@W1 + embed[col]@W2 + dist_e*w_d + b_msg)
// Key restructuring: distribute W_msg over the concat -> per-NODE projections
// (50K rows) instead of per-EDGE GEMM (1.6M rows).

struct GemmPtrs {
  const float* B[4];
  const float* bias[4];
  float* C[4];
};

// Core: C_tile[64 x 128] = A_tile[64 x 128] @ B[128 x 128], fp32, LDS tiled.
// 256 threads; thread microtile 4 rows x 8 cols. K split into two 64-chunks.
__device__ __forceinline__ void gemm_core(const float* __restrict__ A,
                                          const float* __restrict__ B,
                                          int M, int m0, int t,
                                          float (&acc)[4][8],
                                          float (*As)[65], float (*Bs)[128])
{
  const int tx = t & 15;   // col group (8 cols)
  const int ty = t >> 4;   // row group (4 rows)

  for (int kc = 0; kc < 2; ++kc) {
    // Stage A tile: 64 rows x 64 k  (1024 float4, 4 per thread)
#pragma unroll
    for (int q = 0; q < 4; ++q) {
      int idx = t + q * 256;
      int row = idx >> 4;
      int c4  = (idx & 15) * 4;
      float4 v = make_float4(0.f, 0.f, 0.f, 0.f);
      int gr = m0 + row;
      if (gr < M) v = *(const float4*)(A + (size_t)gr * 128 + kc * 64 + c4);
      As[row][c4 + 0] = v.x; As[row][c4 + 1] = v.y;
      As[row][c4 + 2] = v.z; As[row][c4 + 3] = v.w;
    }
    // Stage B tile: 64 k x 128 n (2048 float4, 8 per thread)
#pragma unroll
    for (int q = 0; q < 8; ++q) {
      int idx = t + q * 256;
      int row = idx >> 5;
      int c4  = (idx & 31) * 4;
      *(float4*)(&Bs[row][c4]) = *(const float4*)(B + (size_t)(kc * 64 + row) * 128 + c4);
    }
    __syncthreads();

#pragma unroll 8
    for (int k = 0; k < 64; ++k) {
      float av[4];
#pragma unroll
      for (int i = 0; i < 4; ++i) av[i] = As[ty * 4 + i][k];
      float4 b0 = *(const float4*)(&Bs[k][tx * 8]);
      float4 b1 = *(const float4*)(&Bs[k][tx * 8 + 4]);
      float bv[8] = {b0.x, b0.y, b0.z, b0.w, b1.x, b1.y, b1.z, b1.w};
#pragma unroll
      for (int i = 0; i < 4; ++i)
#pragma unroll
        for (int j = 0; j < 8; ++j) acc[i][j] = fmaf(av[i], bv[j], acc[i][j]);
    }
    __syncthreads();
  }
}

// Phase A: 4 projections in one launch (blockIdx.y picks weight/bias/output)
__global__ __launch_bounds__(256) void gemm_proj(const float* __restrict__ A, int M, GemmPtrs p)
{
  const int gb = blockIdx.y;
  const float* __restrict__ B    = p.B[gb];
  const float* __restrict__ bias = p.bias[gb];
  float* __restrict__ C          = p.C[gb];
  const int m0 = blockIdx.x * 64;
  const int t  = threadIdx.x;

  __shared__ float As[64][65];
  __shared__ float Bs[64][128];

  float acc[4][8];
#pragma unroll
  for (int i = 0; i < 4; ++i)
#pragma unroll
    for (int j = 0; j < 8; ++j) acc[i][j] = 0.f;

  gemm_core(A, B, M, m0, t, acc, As, Bs);

  const int tx = t & 15, ty = t >> 4;
  float bv[8];
#pragma unroll
  for (int j = 0; j < 8; ++j) bv[j] = bias ? bias[tx * 8 + j] : 0.f;
#pragma unroll
  for (int i = 0; i < 4; ++i) {
    int gr = m0 + ty * 4 + i;
    if (gr < M) {
      float4 o0, o1;
      o0.x = acc[i][0] + bv[0]; o0.y = acc[i][1] + bv[1];
      o0.z = acc[i][2] + bv[2]; o0.w = acc[i][3] + bv[3];
      o1.x = acc[i][4] + bv[4]; o1.y = acc[i][5] + bv[5];
      o1.z = acc[i][6] + bv[6]; o1.w = acc[i][7] + bv[7];
      *(float4*)(C + (size_t)gr * 128 + tx * 8)     = o0;
      *(float4*)(C + (size_t)gr * 128 + tx * 8 + 4) = o1;
    }
  }
}

// Phase C: out = Pres(d_out) + relu(aggr@Wu2 + U1b)   (b_upd folded into U1b)
__global__ __launch_bounds__(256) void gemm_upd(const float* __restrict__ A, int M,
                                                const float* __restrict__ B,
                                                const float* __restrict__ U,
                                                float* __restrict__ C)
{
  const int m0 = blockIdx.x * 64;
  const int t  = threadIdx.x;

  __shared__ float As[64][65];
  __shared__ float Bs[64][128];

  float acc[4][8];
#pragma unroll
  for (int i = 0; i < 4; ++i)
#pragma unroll
    for (int j = 0; j < 8; ++j) acc[i][j] = 0.f;

  gemm_core(A, B, M, m0, t, acc, As, Bs);

  const int tx = t & 15, ty = t >> 4;
#pragma unroll
  for (int i = 0; i < 4; ++i) {
    int gr = m0 + ty * 4 + i;
    if (gr < M) {
      size_t base = (size_t)gr * 128 + tx * 8;
      float4 u0 = *(const float4*)(U + base);
      float4 u1 = *(const float4*)(U + base + 4);
      float4 r0 = *(const float4*)(C + base);
      float4 r1 = *(const float4*)(C + base + 4);
      float4 o0, o1;
      o0.x = r0.x + fmaxf(acc[i][0] + u0.x, 0.f);
      o0.y = r0.y + fmaxf(acc[i][1] + u0.y, 0.f);
      o0.z = r0.z + fmaxf(acc[i][2] + u0.z, 0.f);
      o0.w = r0.w + fmaxf(acc[i][3] + u0.w, 0.f);
      o1.x = r1.x + fmaxf(acc[i][4] + u1.x, 0.f);
      o1.y = r1.y + fmaxf(acc[i][5] + u1.y, 0.f);
      o1.z = r1.z + fmaxf(acc[i][6] + u1.z, 0.f);
      o1.w = r1.w + fmaxf(acc[i][7] + u1.w, 0.f);
      *(float4*)(C + base)     = o0;
      *(float4*)(C + base + 4) = o1;
    }
  }
}

// Phase B: one wave per edge; lane handles 2 channels.
// msg = relu(P1[row] + P2b[col] + dist*w_d); atomicAdd into aggr[col].
__global__ __launch_bounds__(256) void edge_msg(const int* __restrict__ ei, int E,
                                                const float* __restrict__ pos,
                                                const float* __restrict__ P1,
                                                const float* __restrict__ P2b,
                                                const float* __restrict__ wd,
                                                float* __restrict__ aggr)
{
  int e = blockIdx.x * 4 + (threadIdx.x >> 6);
  if (e >= E) return;
  const int lane = threadIdx.x & 63;

  const int r = ei[e];
  const int c = ei[E + e];

  float dx = pos[3 * r + 0] - pos[3 * c + 0];
  float dy = pos[3 * r + 1] - pos[3 * c + 1];
  float dz = pos[3 * r + 2] - pos[3 * c + 2];
  float dist = dx * dx + dy * dy + dz * dz;

  const int ch = lane * 2;
  float2 p1 = *(const float2*)(P1 + (size_t)r * 128 + ch);
  float2 p2 = *(const float2*)(P2b + (size_t)c * 128 + ch);
  float2 w  = *(const float2*)(wd + ch);

  float v0 = fmaxf(fmaf(dist, w.x, p1.x + p2.x), 0.f);
  float v1 = fmaxf(fmaf(dist, w.y, p1.y + p2.y), 0.f);

  atomicAdd(aggr + (size_t)c * 128 + ch,     v0);
  atomicAdd(aggr + (size_t)c * 128 + ch + 1, v1);
}

extern "C" void kernel_launch(void* const* d_in, const int* in_sizes, int n_in,
                              void* d_out, int out_size, void* d_ws, size_t ws_size,
                              hipStream_t stream)
{
  const float* embed = (const float*)d_in[0];
  const float* pos   = (const float*)d_in[1];
  const int*   ei    = (const int*)d_in[2];
  const float* W_res = (const float*)d_in[3];
  const float* W_msg = (const float*)d_in[4];
  const float* b_msg = (const float*)d_in[5];
  const float* W_upd = (const float*)d_in[6];
  const float* b_upd = (const float*)d_in[7];
  float* out = (float*)d_out;

  const int M = in_sizes[0] / 128;   // 50000 nodes
  const int E = in_sizes[2] / 2;     // 1.6M edges

  // Workspace: P1, P2b, U1b, aggr — 4 x M x 128 fp32 = 102.4 MB
  float* P1   = (float*)d_ws;
  float* P2b  = P1  + (size_t)M * 128;
  float* U1b  = P2b + (size_t)M * 128;
  float* aggr = U1b + (size_t)M * 128;

  hipMemsetAsync(aggr, 0, (size_t)M * 128 * sizeof(float), stream);

  GemmPtrs p;
  p.B[0] = W_msg;             p.bias[0] = nullptr; p.C[0] = P1;   // embed@W1
  p.B[1] = W_msg + 128 * 128; p.bias[1] = b_msg;   p.C[1] = P2b;  // embed@W2 + b_msg
  p.B[2] = W_upd;             p.bias[2] = b_upd;   p.C[2] = U1b;  // embed@Wu1 + b_upd
  p.B[3] = W_res;             p.bias[3] = nullptr; p.C[3] = out;  // embed@W_res -> d_out

  dim3 gridA((M + 63) / 64, 4);
  gemm_proj<<<gridA, 256, 0, stream>>>(embed, M, p);

  int nb = (E + 3) / 4;
  edge_msg<<<nb, 256, 0, stream>>>(ei, E, pos, P1, P2b, W_msg + 256 * 128, aggr);

  gemm_upd<<<(M + 63) / 64, 256, 0, stream>>>(aggr, M, W_upd + 128 * 128, U1b, out);
}

// Round 2
// 553.132 us; speedup vs baseline: 2.7909x; 2.7909x over previous
//
#include <hip/hip_runtime.h>
#include <hip/hip_bf16.h>
#include <cstdint>

// EquivariantMPLayer restructured:
//   out = embed@W_res + relu(embed@Wu1 + aggr@Wu2 + b_upd)
//   aggr[c] = sum_{e: col[e]==c} relu(P1[row_e] + P2b[c] + dist_e*w_d)
//   with P1 = embed@W1, P2b = embed@W2 + b_msg  (W_msg distributed over concat)
// Edge phase uses counting-sort (CSR) to aggregate in registers — no value atomics.

struct GemmPtrs {
  const float* B[3];
  const float* bias[3];
  float* C[3];
};

// C_tile[64 x 128] += A_tile[64 x 128] @ B[128 x 128], fp32 LDS-tiled.
// 256 threads; microtile 4 rows x 8 cols; K in two 64-chunks.
__device__ __forceinline__ void gemm_core(const float* __restrict__ A,
                                          const float* __restrict__ B,
                                          int M, int m0, int t,
                                          float (&acc)[4][8],
                                          float (*As)[65], float (*Bs)[128])
{
  const int tx = t & 15;
  const int ty = t >> 4;

  for (int kc = 0; kc < 2; ++kc) {
#pragma unroll
    for (int q = 0; q < 4; ++q) {
      int idx = t + q * 256;
      int row = idx >> 4;
      int c4  = (idx & 15) * 4;
      float4 v = make_float4(0.f, 0.f, 0.f, 0.f);
      int gr = m0 + row;
      if (gr < M) v = *(const float4*)(A + (size_t)gr * 128 + kc * 64 + c4);
      As[row][c4 + 0] = v.x; As[row][c4 + 1] = v.y;
      As[row][c4 + 2] = v.z; As[row][c4 + 3] = v.w;
    }
#pragma unroll
    for (int q = 0; q < 8; ++q) {
      int idx = t + q * 256;
      int row = idx >> 5;
      int c4  = (idx & 31) * 4;
      *(float4*)(&Bs[row][c4]) = *(const float4*)(B + (size_t)(kc * 64 + row) * 128 + c4);
    }
    __syncthreads();

#pragma unroll 8
    for (int k = 0; k < 64; ++k) {
      float av[4];
#pragma unroll
      for (int i = 0; i < 4; ++i) av[i] = As[ty * 4 + i][k];
      float4 b0 = *(const float4*)(&Bs[k][tx * 8]);
      float4 b1 = *(const float4*)(&Bs[k][tx * 8 + 4]);
      float bv[8] = {b0.x, b0.y, b0.z, b0.w, b1.x, b1.y, b1.z, b1.w};
#pragma unroll
      for (int i = 0; i < 4; ++i)
#pragma unroll
        for (int j = 0; j < 8; ++j) acc[i][j] = fmaf(av[i], bv[j], acc[i][j]);
    }
    __syncthreads();
  }
}

// Node projections: P1 = embed@W1, P2b = embed@W2 + b_msg, Pres = embed@W_res -> d_out
__global__ __launch_bounds__(256) void gemm_proj(const float* __restrict__ A, int M, GemmPtrs p)
{
  const int gb = blockIdx.y;
  const float* __restrict__ B    = p.B[gb];
  const float* __restrict__ bias = p.bias[gb];
  float* __restrict__ C          = p.C[gb];
  const int m0 = blockIdx.x * 64;
  const int t  = threadIdx.x;

  __shared__ float As[64][65];
  __shared__ float Bs[64][128];

  float acc[4][8];
#pragma unroll
  for (int i = 0; i < 4; ++i)
#pragma unroll
    for (int j = 0; j < 8; ++j) acc[i][j] = 0.f;

  gemm_core(A, B, M, m0, t, acc, As, Bs);

  const int tx = t & 15, ty = t >> 4;
  float bv[8];
#pragma unroll
  for (int j = 0; j < 8; ++j) bv[j] = bias ? bias[tx * 8 + j] : 0.f;
#pragma unroll
  for (int i = 0; i < 4; ++i) {
    int gr = m0 + ty * 4 + i;
    if (gr < M) {
      float4 o0, o1;
      o0.x = acc[i][0] + bv[0]; o0.y = acc[i][1] + bv[1];
      o0.z = acc[i][2] + bv[2]; o0.w = acc[i][3] + bv[3];
      o1.x = acc[i][4] + bv[4]; o1.y = acc[i][5] + bv[5];
      o1.z = acc[i][6] + bv[6]; o1.w = acc[i][7] + bv[7];
      *(float4*)(C + (size_t)gr * 128 + tx * 8)     = o0;
      *(float4*)(C + (size_t)gr * 128 + tx * 8 + 4) = o1;
    }
  }
}

// Final: out = Pres(in d_out) + relu(embed@Wu1 + aggr@Wu2 + b_upd)  (K=256 fused)
__global__ __launch_bounds__(256) void gemm_upd(const float* __restrict__ A1,
                                                const float* __restrict__ A2, int M,
                                                const float* __restrict__ B1,
                                                const float* __restrict__ B2,
                                                const float* __restrict__ bias,
                                                float* __restrict__ C)
{
  const int m0 = blockIdx.x * 64;
  const int t  = threadIdx.x;

  __shared__ float As[64][65];
  __shared__ float Bs[64][128];

  float acc[4][8];
#pragma unroll
  for (int i = 0; i < 4; ++i)
#pragma unroll
    for (int j = 0; j < 8; ++j) acc[i][j] = 0.f;

  gemm_core(A1, B1, M, m0, t, acc, As, Bs);
  gemm_core(A2, B2, M, m0, t, acc, As, Bs);

  const int tx = t & 15, ty = t >> 4;
  float bv[8];
#pragma unroll
  for (int j = 0; j < 8; ++j) bv[j] = bias[tx * 8 + j];
#pragma unroll
  for (int i = 0; i < 4; ++i) {
    int gr = m0 + ty * 4 + i;
    if (gr < M) {
      size_t base = (size_t)gr * 128 + tx * 8;
      float4 r0 = *(const float4*)(C + base);
      float4 r1 = *(const float4*)(C + base + 4);
      float4 o0, o1;
      o0.x = r0.x + fmaxf(acc[i][0] + bv[0], 0.f);
      o0.y = r0.y + fmaxf(acc[i][1] + bv[1], 0.f);
      o0.z = r0.z + fmaxf(acc[i][2] + bv[2], 0.f);
      o0.w = r0.w + fmaxf(acc[i][3] + bv[3], 0.f);
      o1.x = r1.x + fmaxf(acc[i][4] + bv[4], 0.f);
      o1.y = r1.y + fmaxf(acc[i][5] + bv[5], 0.f);
      o1.z = r1.z + fmaxf(acc[i][6] + bv[6], 0.f);
      o1.w = r1.w + fmaxf(acc[i][7] + bv[7], 0.f);
      *(float4*)(C + base)     = o0;
      *(float4*)(C + base + 4) = o1;
    }
  }
}

// --- CSR build: histogram -> exclusive scan -> scatter {row,dist} records ---

__global__ __launch_bounds__(256) void hist_kernel(const int* __restrict__ col, int E,
                                                   int* __restrict__ counts)
{
  int e = blockIdx.x * 256 + threadIdx.x;
  if (e < E) atomicAdd(counts + col[e], 1);
}

// Single-block exclusive scan over n counters. Writes offsets[0..n] and
// transforms counts[] in place into a scatter cursor (== offsets[0..n-1]).
__global__ __launch_bounds__(1024) void scan_kernel(int* __restrict__ counts,
                                                    int* __restrict__ offsets, int n)
{
  __shared__ int wsum[16];
  __shared__ int wpre[16];
  __shared__ int s_carry, s_total;
  const int t = threadIdx.x;
  const int lane = t & 63, wid = t >> 6;
  if (t == 0) s_carry = 0;
  __syncthreads();
  for (int base = 0; base < n; base += 1024) {
    int i = base + t;
    int v = (i < n) ? counts[i] : 0;
    int incl = v;
#pragma unroll
    for (int d = 1; d < 64; d <<= 1) {
      int u = __shfl_up(incl, d, 64);
      if (lane >= d) incl += u;
    }
    if (lane == 63) wsum[wid] = incl;
    __syncthreads();
    if (t == 0) {
      int run = 0;
#pragma unroll
      for (int j = 0; j < 16; ++j) { int x = wsum[j]; wpre[j] = run; run += x; }
      s_total = run;
    }
    __syncthreads();
    int excl = s_carry + wpre[wid] + incl - v;
    if (i < n) { offsets[i] = excl; counts[i] = excl; }
    int ctot = s_total;
    __syncthreads();
    if (t == 0) s_carry += ctot;
    __syncthreads();
  }
  if (t == 0) offsets[n] = s_carry;
}

__global__ __launch_bounds__(256) void scatter_edges(const int* __restrict__ ei, int E,
                                                     const float* __restrict__ pos,
                                                     int* __restrict__ cursor,
                                                     int2* __restrict__ recs)
{
  int e = blockIdx.x * 256 + threadIdx.x;
  if (e >= E) return;
  int r = ei[e], c = ei[E + e];
  float dx = pos[3 * r + 0] - pos[3 * c + 0];
  float dy = pos[3 * r + 1] - pos[3 * c + 1];
  float dz = pos[3 * r + 2] - pos[3 * c + 2];
  float dist = dx * dx + dy * dy + dz * dz;
  int slot = atomicAdd(cursor + c, 1);
  recs[slot] = make_int2(r, __float_as_int(dist));
}

// One wave per node; lane owns 2 channels. Register accumulation, single write.
__global__ __launch_bounds__(256) void aggregate(const int* __restrict__ offsets,
                                                 const int2* __restrict__ recs,
                                                 const float* __restrict__ P1,
                                                 const float* __restrict__ P2b,
                                                 const float* __restrict__ wd,
                                                 float* __restrict__ aggr, int M)
{
  int n = blockIdx.x * 4 + (threadIdx.x >> 6);
  if (n >= M) return;
  const int lane = threadIdx.x & 63;
  const int ch = lane * 2;

  float2 w  = *(const float2*)(wd + ch);
  float2 p2 = *(const float2*)(P2b + (size_t)n * 128 + ch);

  int i   = offsets[n];
  int end = offsets[n + 1];
  float a0 = 0.f, a1 = 0.f;

  for (; i + 2 <= end; i += 2) {
    int2 e0 = recs[i];
    int2 e1 = recs[i + 1];
    float d0 = __int_as_float(e0.y);
    float d1 = __int_as_float(e1.y);
    float2 q0 = *(const float2*)(P1 + (size_t)e0.x * 128 + ch);
    float2 q1 = *(const float2*)(P1 + (size_t)e1.x * 128 + ch);
    a0 += fmaxf(fmaf(d0, w.x, q0.x + p2.x), 0.f);
    a1 += fmaxf(fmaf(d0, w.y, q0.y + p2.y), 0.f);
    a0 += fmaxf(fmaf(d1, w.x, q1.x + p2.x), 0.f);
    a1 += fmaxf(fmaf(d1, w.y, q1.y + p2.y), 0.f);
  }
  if (i < end) {
    int2 e0 = recs[i];
    float d0 = __int_as_float(e0.y);
    float2 q0 = *(const float2*)(P1 + (size_t)e0.x * 128 + ch);
    a0 += fmaxf(fmaf(d0, w.x, q0.x + p2.x), 0.f);
    a1 += fmaxf(fmaf(d0, w.y, q0.y + p2.y), 0.f);
  }
  *(float2*)(aggr + (size_t)n * 128 + ch) = make_float2(a0, a1);
}

extern "C" void kernel_launch(void* const* d_in, const int* in_sizes, int n_in,
                              void* d_out, int out_size, void* d_ws, size_t ws_size,
                              hipStream_t stream)
{
  const float* embed = (const float*)d_in[0];
  const float* pos   = (const float*)d_in[1];
  const int*   ei    = (const int*)d_in[2];
  const float* W_res = (const float*)d_in[3];
  const float* W_msg = (const float*)d_in[4];
  const float* b_msg = (const float*)d_in[5];
  const float* W_upd = (const float*)d_in[6];
  const float* b_upd = (const float*)d_in[7];
  float* out = (float*)d_out;

  const int M = in_sizes[0] / 128;   // 50000 nodes
  const int E = in_sizes[2] / 2;     // 1.6M edges

  // Workspace layout (~90 MB):
  float* P1      = (float*)d_ws;            // M*128
  float* P2b     = P1  + (size_t)M * 128;   // M*128
  float* aggr    = P2b + (size_t)M * 128;   // M*128
  int2*  recs    = (int2*)(aggr + (size_t)M * 128);  // E
  int*   counts  = (int*)(recs + E);        // M  (becomes cursor after scan)
  int*   offsets = counts + M;              // M+1

  hipMemsetAsync(counts, 0, (size_t)M * sizeof(int), stream);

  GemmPtrs p;
  p.B[0] = W_msg;             p.bias[0] = nullptr; p.C[0] = P1;
  p.B[1] = W_msg + 128 * 128; p.bias[1] = b_msg;   p.C[1] = P2b;
  p.B[2] = W_res;             p.bias[2] = nullptr; p.C[2] = out;

  dim3 gridA((M + 63) / 64, 3);
  gemm_proj<<<gridA, 256, 0, stream>>>(embed, M, p);

  int eb = (E + 255) / 256;
  hist_kernel<<<eb, 256, 0, stream>>>(ei + E, E, counts);
  scan_kernel<<<1, 1024, 0, stream>>>(counts, offsets, M);
  scatter_edges<<<eb, 256, 0, stream>>>(ei, E, pos, counts, recs);
  aggregate<<<(M + 3) / 4, 256, 0, stream>>>(offsets, recs, P1, P2b,
                                             W_msg + 256 * 128, aggr, M);

  gemm_upd<<<(M + 63) / 64, 256, 0, stream>>>(embed, aggr, M,
                                              W_upd, W_upd + 128 * 128, b_upd, out);
}

// Round 3
// 453.690 us; speedup vs baseline: 3.4026x; 1.2192x over previous
//
#include <hip/hip_runtime.h>
#include <hip/hip_bf16.h>
#include <cstdint>

// EquivariantMPLayer restructured:
//   out = embed@W_res + relu(embed@Wu1 + aggr@Wu2 + b_upd)
//   aggr[c] = sum_{e: col[e]==c} relu(P1[row_e] + P2b[c] + dist_e*w_d)
//   P1 = embed@W1, P2b = embed@W2 + b_msg   (W_msg distributed over concat)
// Round 3: all GEMMs via bf16 MFMA 16x16x32 (fp32 accum), node features
// carried in bf16 to halve the edge-phase gather traffic. CSR counting-sort
// aggregation (no value atomics).

typedef __bf16 bf16x8 __attribute__((ext_vector_type(8)));
typedef float floatx4 __attribute__((ext_vector_type(4)));

__device__ __forceinline__ float bf2f(uint u) {
  union { uint i; float f; } v; v.i = u << 16; return v.f;
}
__device__ __forceinline__ ushort f2bf(float f) {
  union { float f; uint i; } v; v.f = f;
  uint r = v.i + 0x7fff + ((v.i >> 16) & 1);   // RNE
  return (ushort)(r >> 16);
}
__device__ __forceinline__ bf16x8 load_frag(const ushort* p) {
  uint4 v = *(const uint4*)p;
  return __builtin_bit_cast(bf16x8, v);
}

// ---- casts ----

__global__ __launch_bounds__(256) void cast_embed(const float* __restrict__ in,
                                                  ushort* __restrict__ out, int n4)
{
  int i = blockIdx.x * 256 + threadIdx.x;
  if (i < n4) {
    float4 v = ((const float4*)in)[i];
    ushort4 o;
    o.x = f2bf(v.x); o.y = f2bf(v.y); o.z = f2bf(v.z); o.w = f2bf(v.w);
    ((ushort4*)out)[i] = o;
  }
}

struct WSrc { const float* s[5]; };

// transpose-cast: dst[n*128+k] = bf16(src[k*128+n])  (one 128x128 block per blockIdx)
__global__ __launch_bounds__(256) void cast_wt(WSrc ws, ushort* __restrict__ dst)
{
  const float* s = ws.s[blockIdx.x];
  ushort* d = dst + blockIdx.x * 16384;
  for (int i = threadIdx.x; i < 16384; i += 256) {
    int n = i >> 7, k = i & 127;
    d[i] = f2bf(s[k * 128 + n]);
  }
}

// ---- MFMA GEMMs ----
// Fragment layouts (16x16x32 bf16, verified m89/m120):
//   A: lane l, j  -> A[m = l&15][k = (l>>4)*8 + j]
//   B: lane l, j  -> B[k = (l>>4)*8 + j][n = l&15]
//   D: lane l, i  -> D[m = (l>>4)*4 + i][n = l&15]
// Block = 256 thr = 4 waves; wave owns 32 rows x 32 cols; B frags in registers.

// P1 = Eb@W1t^T, P2b = Eb@W2t^T + b_msg; outputs bf16.
__global__ __launch_bounds__(256) void gemm_proj_mfma(
    const ushort* __restrict__ Ab, int M,
    const ushort* __restrict__ W1t, const ushort* __restrict__ W2t,
    const float* __restrict__ b_msg,
    ushort* __restrict__ P1, ushort* __restrict__ P2b)
{
  const int wv = threadIdx.x >> 6, lane = threadIdx.x & 63;
  const int q = lane >> 4, lr = lane & 15;
  const int m0 = blockIdx.x * 32;
  const int n0 = wv * 32;

  const ushort* Wt[2] = {W1t, W2t};
  bf16x8 bfr[2][2][4];
#pragma unroll
  for (int ws = 0; ws < 2; ++ws)
#pragma unroll
    for (int nt = 0; nt < 2; ++nt) {
      int col = n0 + nt * 16 + lr;
#pragma unroll
      for (int kc = 0; kc < 4; ++kc)
        bfr[ws][nt][kc] = load_frag(Wt[ws] + col * 128 + kc * 32 + q * 8);
    }

  floatx4 z = {0.f, 0.f, 0.f, 0.f};
  floatx4 acc[2][2][2];   // [wset][mt][nt]
#pragma unroll
  for (int ws = 0; ws < 2; ++ws)
#pragma unroll
    for (int mt = 0; mt < 2; ++mt)
#pragma unroll
      for (int nt = 0; nt < 2; ++nt) acc[ws][mt][nt] = z;

  const int r0 = min(m0 + lr, M - 1);
  const int r1 = min(m0 + 16 + lr, M - 1);
#pragma unroll
  for (int kc = 0; kc < 4; ++kc) {
    bf16x8 a0 = load_frag(Ab + (size_t)r0 * 128 + kc * 32 + q * 8);
    bf16x8 a1 = load_frag(Ab + (size_t)r1 * 128 + kc * 32 + q * 8);
#pragma unroll
    for (int ws = 0; ws < 2; ++ws)
#pragma unroll
      for (int nt = 0; nt < 2; ++nt) {
        acc[ws][0][nt] = __builtin_amdgcn_mfma_f32_16x16x32_bf16(a0, bfr[ws][nt][kc], acc[ws][0][nt], 0, 0, 0);
        acc[ws][1][nt] = __builtin_amdgcn_mfma_f32_16x16x32_bf16(a1, bfr[ws][nt][kc], acc[ws][1][nt], 0, 0, 0);
      }
  }

  ushort* Cp[2] = {P1, P2b};
#pragma unroll
  for (int ws = 0; ws < 2; ++ws)
#pragma unroll
    for (int nt = 0; nt < 2; ++nt) {
      int col = n0 + nt * 16 + lr;
      float bias = (ws == 1) ? b_msg[col] : 0.f;
#pragma unroll
      for (int mt = 0; mt < 2; ++mt)
#pragma unroll
        for (int i = 0; i < 4; ++i) {
          int r = m0 + mt * 16 + q * 4 + i;
          if (r < M) Cp[ws][(size_t)r * 128 + col] = f2bf(acc[ws][mt][nt][i] + bias);
        }
    }
}

// out = Eb@Wrt^T + relu(Eb@Wu1t^T + Gb@Wu2t^T + b_upd), fp32 out.
__global__ __launch_bounds__(256) void gemm_upd_mfma(
    const ushort* __restrict__ Eb, const ushort* __restrict__ Gb, int M,
    const ushort* __restrict__ Wu1t, const ushort* __restrict__ Wu2t,
    const ushort* __restrict__ Wrt, const float* __restrict__ b_upd,
    float* __restrict__ out)
{
  const int wv = threadIdx.x >> 6, lane = threadIdx.x & 63;
  const int q = lane >> 4, lr = lane & 15;
  const int m0 = blockIdx.x * 32;
  const int n0 = wv * 32;

  bf16x8 b1[2][4], b2[2][4], br[2][4];
#pragma unroll
  for (int nt = 0; nt < 2; ++nt) {
    int col = n0 + nt * 16 + lr;
#pragma unroll
    for (int kc = 0; kc < 4; ++kc) {
      b1[nt][kc] = load_frag(Wu1t + col * 128 + kc * 32 + q * 8);
      b2[nt][kc] = load_frag(Wu2t + col * 128 + kc * 32 + q * 8);
      br[nt][kc] = load_frag(Wrt  + col * 128 + kc * 32 + q * 8);
    }
  }

  floatx4 z = {0.f, 0.f, 0.f, 0.f};
  floatx4 acc_u[2][2], acc_r[2][2];
#pragma unroll
  for (int mt = 0; mt < 2; ++mt)
#pragma unroll
    for (int nt = 0; nt < 2; ++nt) { acc_u[mt][nt] = z; acc_r[mt][nt] = z; }

  const int r0 = min(m0 + lr, M - 1);
  const int r1 = min(m0 + 16 + lr, M - 1);
#pragma unroll
  for (int kc = 0; kc < 4; ++kc) {
    bf16x8 ae0 = load_frag(Eb + (size_t)r0 * 128 + kc * 32 + q * 8);
    bf16x8 ae1 = load_frag(Eb + (size_t)r1 * 128 + kc * 32 + q * 8);
    bf16x8 ag0 = load_frag(Gb + (size_t)r0 * 128 + kc * 32 + q * 8);
    bf16x8 ag1 = load_frag(Gb + (size_t)r1 * 128 + kc * 32 + q * 8);
#pragma unroll
    for (int nt = 0; nt < 2; ++nt) {
      acc_u[0][nt] = __builtin_amdgcn_mfma_f32_16x16x32_bf16(ae0, b1[nt][kc], acc_u[0][nt], 0, 0, 0);
      acc_u[1][nt] = __builtin_amdgcn_mfma_f32_16x16x32_bf16(ae1, b1[nt][kc], acc_u[1][nt], 0, 0, 0);
      acc_u[0][nt] = __builtin_amdgcn_mfma_f32_16x16x32_bf16(ag0, b2[nt][kc], acc_u[0][nt], 0, 0, 0);
      acc_u[1][nt] = __builtin_amdgcn_mfma_f32_16x16x32_bf16(ag1, b2[nt][kc], acc_u[1][nt], 0, 0, 0);
      acc_r[0][nt] = __builtin_amdgcn_mfma_f32_16x16x32_bf16(ae0, br[nt][kc], acc_r[0][nt], 0, 0, 0);
      acc_r[1][nt] = __builtin_amdgcn_mfma_f32_16x16x32_bf16(ae1, br[nt][kc], acc_r[1][nt], 0, 0, 0);
    }
  }

#pragma unroll
  for (int nt = 0; nt < 2; ++nt) {
    int col = n0 + nt * 16 + lr;
    float bias = b_upd[col];
#pragma unroll
    for (int mt = 0; mt < 2; ++mt)
#pragma unroll
      for (int i = 0; i < 4; ++i) {
        int r = m0 + mt * 16 + q * 4 + i;
        if (r < M)
          out[(size_t)r * 128 + col] = acc_r[mt][nt][i] + fmaxf(acc_u[mt][nt][i] + bias, 0.f);
      }
  }
}

// ---- CSR build ----

__global__ __launch_bounds__(256) void hist_kernel(const int* __restrict__ col, int E,
                                                   int* __restrict__ counts)
{
  int e = blockIdx.x * 256 + threadIdx.x;
  if (e < E) atomicAdd(counts + col[e], 1);
}

__global__ __launch_bounds__(1024) void scan_kernel(int* __restrict__ counts,
                                                    int* __restrict__ offsets, int n)
{
  __shared__ int wsum[16];
  __shared__ int wpre[16];
  __shared__ int s_carry, s_total;
  const int t = threadIdx.x;
  const int lane = t & 63, wid = t >> 6;
  if (t == 0) s_carry = 0;
  __syncthreads();
  for (int base = 0; base < n; base += 1024) {
    int i = base + t;
    int v = (i < n) ? counts[i] : 0;
    int incl = v;
#pragma unroll
    for (int d = 1; d < 64; d <<= 1) {
      int u = __shfl_up(incl, d, 64);
      if (lane >= d) incl += u;
    }
    if (lane == 63) wsum[wid] = incl;
    __syncthreads();
    if (t == 0) {
      int run = 0;
#pragma unroll
      for (int j = 0; j < 16; ++j) { int x = wsum[j]; wpre[j] = run; run += x; }
      s_total = run;
    }
    __syncthreads();
    int excl = s_carry + wpre[wid] + incl - v;
    if (i < n) { offsets[i] = excl; counts[i] = excl; }
    int ctot = s_total;
    __syncthreads();
    if (t == 0) s_carry += ctot;
    __syncthreads();
  }
  if (t == 0) offsets[n] = s_carry;
}

__global__ __launch_bounds__(256) void scatter_edges(const int* __restrict__ ei, int E,
                                                     const float* __restrict__ pos,
                                                     int* __restrict__ cursor,
                                                     int2* __restrict__ recs)
{
  int e = blockIdx.x * 256 + threadIdx.x;
  if (e >= E) return;
  int r = ei[e], c = ei[E + e];
  float dx = pos[3 * r + 0] - pos[3 * c + 0];
  float dy = pos[3 * r + 1] - pos[3 * c + 1];
  float dz = pos[3 * r + 2] - pos[3 * c + 2];
  float dist = dx * dx + dy * dy + dz * dz;
  int slot = atomicAdd(cursor + c, 1);
  recs[slot] = make_int2(r, __float_as_int(dist));
}

// One wave per node; lane owns 2 channels (bf16 gathers, fp32 accum, bf16 out).
__global__ __launch_bounds__(256) void aggregate(const int* __restrict__ offsets,
                                                 const int2* __restrict__ recs,
                                                 const ushort* __restrict__ P1,
                                                 const ushort* __restrict__ P2b,
                                                 const float* __restrict__ wd,
                                                 ushort* __restrict__ aggr, int M)
{
  int n = blockIdx.x * 4 + (threadIdx.x >> 6);
  if (n >= M) return;
  const int lane = threadIdx.x & 63;
  const int ch = lane * 2;

  float2 w = *(const float2*)(wd + ch);
  uint p2u = *(const uint*)(P2b + (size_t)n * 128 + ch);
  float p2x = bf2f(p2u & 0xffffu), p2y = bf2f(p2u >> 16);

  int i   = offsets[n];
  int end = offsets[n + 1];
  float a0 = 0.f, a1 = 0.f;

  for (; i + 2 <= end; i += 2) {
    int2 e0 = recs[i];
    int2 e1 = recs[i + 1];
    float d0 = __int_as_float(e0.y);
    float d1 = __int_as_float(e1.y);
    uint q0 = *(const uint*)(P1 + (size_t)e0.x * 128 + ch);
    uint q1 = *(const uint*)(P1 + (size_t)e1.x * 128 + ch);
    a0 += fmaxf(fmaf(d0, w.x, bf2f(q0 & 0xffffu) + p2x), 0.f);
    a1 += fmaxf(fmaf(d0, w.y, bf2f(q0 >> 16)     + p2y), 0.f);
    a0 += fmaxf(fmaf(d1, w.x, bf2f(q1 & 0xffffu) + p2x), 0.f);
    a1 += fmaxf(fmaf(d1, w.y, bf2f(q1 >> 16)     + p2y), 0.f);
  }
  if (i < end) {
    int2 e0 = recs[i];
    float d0 = __int_as_float(e0.y);
    uint q0 = *(const uint*)(P1 + (size_t)e0.x * 128 + ch);
    a0 += fmaxf(fmaf(d0, w.x, bf2f(q0 & 0xffffu) + p2x), 0.f);
    a1 += fmaxf(fmaf(d0, w.y, bf2f(q0 >> 16)     + p2y), 0.f);
  }
  ushort2 o; o.x = f2bf(a0); o.y = f2bf(a1);
  *(ushort2*)(aggr + (size_t)n * 128 + ch) = o;
}

extern "C" void kernel_launch(void* const* d_in, const int* in_sizes, int n_in,
                              void* d_out, int out_size, void* d_ws, size_t ws_size,
                              hipStream_t stream)
{
  const float* embed = (const float*)d_in[0];
  const float* pos   = (const float*)d_in[1];
  const int*   ei    = (const int*)d_in[2];
  const float* W_res = (const float*)d_in[3];
  const float* W_msg = (const float*)d_in[4];
  const float* b_msg = (const float*)d_in[5];
  const float* W_upd = (const float*)d_in[6];
  const float* b_upd = (const float*)d_in[7];
  float* out = (float*)d_out;

  const int M = in_sizes[0] / 128;   // 50000
  const int E = in_sizes[2] / 2;     // 1.6M

  // Workspace (~65 MB)
  ushort* Eb   = (ushort*)d_ws;               // M*128 bf16 embed
  ushort* P1b  = Eb  + (size_t)M * 128;
  ushort* P2b  = P1b + (size_t)M * 128;
  ushort* Gb   = P2b + (size_t)M * 128;       // aggr bf16
  ushort* Wt   = Gb  + (size_t)M * 128;       // 5 x 128x128 transposed bf16
  int2*   recs = (int2*)(Wt + 5 * 16384);     // E
  int*   counts  = (int*)(recs + E);          // M
  int*   offsets = counts + M;                // M+1

  hipMemsetAsync(counts, 0, (size_t)M * sizeof(int), stream);

  int n4 = M * 128 / 4;
  cast_embed<<<(n4 + 255) / 256, 256, 0, stream>>>(embed, Eb, n4);

  WSrc wsrc;
  wsrc.s[0] = W_msg;               // W1
  wsrc.s[1] = W_msg + 128 * 128;   // W2
  wsrc.s[2] = W_res;               // Wres
  wsrc.s[3] = W_upd;               // Wu1
  wsrc.s[4] = W_upd + 128 * 128;   // Wu2
  cast_wt<<<5, 256, 0, stream>>>(wsrc, Wt);

  int rt = (M + 31) / 32;
  gemm_proj_mfma<<<rt, 256, 0, stream>>>(Eb, M, Wt, Wt + 16384, b_msg, P1b, P2b);

  int eb = (E + 255) / 256;
  hist_kernel<<<eb, 256, 0, stream>>>(ei + E, E, counts);
  scan_kernel<<<1, 1024, 0, stream>>>(counts, offsets, M);
  scatter_edges<<<eb, 256, 0, stream>>>(ei, E, pos, counts, recs);
  aggregate<<<(M + 3) / 4, 256, 0, stream>>>(offsets, recs, P1b, P2b,
                                             W_msg + 256 * 128, Gb, M);

  gemm_upd_mfma<<<rt, 256, 0, stream>>>(Eb, Gb, M, Wt + 3 * 16384, Wt + 4 * 16384,
                                        Wt + 2 * 16384, b_upd, out);
}

// Round 5
// 408.537 us; speedup vs baseline: 3.7787x; 1.1105x over previous
//
#include <hip/hip_runtime.h>
#include <hip/hip_bf16.h>
#include <cstdint>

// EquivariantMPLayer restructured:
//   out = embed@W_res + relu(embed@Wu1 + aggr@Wu2 + b_upd)
//   aggr[c] = sum_{e: col[e]==c} relu(P1[row_e] + P2b[c] + dist_e*w_d)
//   P1 = embed@W1, P2b = embed@W2 + b_msg   (W_msg distributed over concat)
// Round 5 (= Round 4 retry): fused launches (cast+hist+castwt | scan |
// gemm_proj+scatter | aggregate | gemm_upd), int4-vectorized scan, unroll-4
// aggregate with nontemporal streaming of edge records.
// NT builtins need native ext_vector types, not HIP_vector_type classes.

typedef __bf16 bf16x8 __attribute__((ext_vector_type(8)));
typedef float floatx4 __attribute__((ext_vector_type(4)));
typedef int intx2 __attribute__((ext_vector_type(2)));
typedef int intx4 __attribute__((ext_vector_type(4)));

__device__ __forceinline__ float bf2f(uint u) {
  union { uint i; float f; } v; v.i = u << 16; return v.f;
}
__device__ __forceinline__ ushort f2bf(float f) {
  union { float f; uint i; } v; v.f = f;
  uint r = v.i + 0x7fff + ((v.i >> 16) & 1);   // RNE
  return (ushort)(r >> 16);
}
__device__ __forceinline__ bf16x8 load_frag(const ushort* p) {
  uint4 v = *(const uint4*)p;
  return __builtin_bit_cast(bf16x8, v);
}

struct WSrc { const float* s[5]; };

// ---- K1: cast embed to bf16 + histogram of edge targets + weight transpose-cast ----
__global__ __launch_bounds__(256) void k1_cast_hist(
    const float* __restrict__ embed, ushort* __restrict__ Eb, int n4,
    const int* __restrict__ col, int E, int* __restrict__ counts,
    WSrc ws, ushort* __restrict__ Wt, int nb_main)
{
  if ((int)blockIdx.x >= nb_main) {
    int wb = blockIdx.x - nb_main;
    const float* s = ws.s[wb];
    ushort* d = Wt + wb * 16384;
    for (int i = threadIdx.x; i < 16384; i += 256) {
      int k = i >> 7, n = i & 127;
      d[n * 128 + k] = f2bf(s[i]);
    }
    return;
  }
  int i = blockIdx.x * 256 + threadIdx.x;
  if (i < n4) {
    float4 v = ((const float4*)embed)[i];
    ushort4 o;
    o.x = f2bf(v.x); o.y = f2bf(v.y); o.z = f2bf(v.z); o.w = f2bf(v.w);
    ((ushort4*)Eb)[i] = o;
  }
  if (i < E) atomicAdd(counts + col[i], 1);
}

// ---- K2: exclusive scan (int4-vectorized, 4096 elems/tile) ----
__global__ __launch_bounds__(1024) void scan_kernel(int* __restrict__ counts,
                                                    int* __restrict__ offsets, int n)
{
  __shared__ int wsum[16];
  __shared__ int wpre[16];
  __shared__ int s_carry, s_total;
  const int t = threadIdx.x;
  const int lane = t & 63, wid = t >> 6;
  if (t == 0) s_carry = 0;
  __syncthreads();

  const int n4 = (n + 3) >> 2;
  for (int b4 = 0; b4 < n4; b4 += 1024) {
    int i4 = b4 + t;
    int base = i4 * 4;
    int4 v = make_int4(0, 0, 0, 0);
    if (base + 3 < n) v = ((const int4*)counts)[i4];
    else if (base < n) {
      v.x = counts[base];
      if (base + 1 < n) v.y = counts[base + 1];
      if (base + 2 < n) v.z = counts[base + 2];
    }
    int tsum = v.x + v.y + v.z + v.w;
    int incl = tsum;
#pragma unroll
    for (int d = 1; d < 64; d <<= 1) {
      int u = __shfl_up(incl, d, 64);
      if (lane >= d) incl += u;
    }
    if (lane == 63) wsum[wid] = incl;
    __syncthreads();
    if (t == 0) {
      int run = 0;
#pragma unroll
      for (int j = 0; j < 16; ++j) { int x = wsum[j]; wpre[j] = run; run += x; }
      s_total = run;
    }
    __syncthreads();
    int excl = s_carry + wpre[wid] + incl - tsum;
    if (base + 3 < n) {
      int4 o;
      o.x = excl; o.y = o.x + v.x; o.z = o.y + v.y; o.w = o.z + v.z;
      ((int4*)offsets)[i4] = o;
      ((int4*)counts)[i4] = o;
    } else if (base < n) {
      int run = excl;
      offsets[base] = run; counts[base] = run; run += v.x;
      if (base + 1 < n) { offsets[base + 1] = run; counts[base + 1] = run; run += v.y; }
      if (base + 2 < n) { offsets[base + 2] = run; counts[base + 2] = run; }
    }
    __syncthreads();
    if (t == 0) s_carry += s_total;
    __syncthreads();
  }
  if (t == 0) offsets[n] = s_carry;
}

// ---- K3: gemm_proj (MFMA) + scatter, fused via blockIdx split ----
// Fragment layouts (16x16x32 bf16, verified m89/m120):
//   A: lane l, j -> A[m=l&15][k=(l>>4)*8+j];  B: lane l, j -> B[k=(l>>4)*8+j][n=l&15]
//   D: lane l, i -> D[m=(l>>4)*4+i][n=l&15]
__global__ __launch_bounds__(256) void k3_proj_scatter(
    const ushort* __restrict__ Ab, int M, int rt,
    const ushort* __restrict__ W1t, const ushort* __restrict__ W2t,
    const float* __restrict__ b_msg,
    ushort* __restrict__ P1, ushort* __restrict__ P2b,
    const int* __restrict__ ei, int E, const float* __restrict__ pos,
    int* __restrict__ cursor, int2* __restrict__ recs)
{
  if ((int)blockIdx.x >= rt) {
    // ---- scatter: 4 edges/thread, int4 edge loads, NT rec stores ----
    int e4 = (blockIdx.x - rt) * 256 + threadIdx.x;
    int e0 = e4 * 4;
    if (e0 >= E) return;
    int4 rv = ((const int4*)ei)[e4];
    int4 cv = ((const int4*)(ei + E))[e4];
    int rr[4] = {rv.x, rv.y, rv.z, rv.w};
    int cc[4] = {cv.x, cv.y, cv.z, cv.w};
#pragma unroll
    for (int j = 0; j < 4; ++j) {
      if (e0 + j >= E) break;
      int r = rr[j], c = cc[j];
      float dx = pos[3 * r + 0] - pos[3 * c + 0];
      float dy = pos[3 * r + 1] - pos[3 * c + 1];
      float dz = pos[3 * r + 2] - pos[3 * c + 2];
      float dist = dx * dx + dy * dy + dz * dz;
      int slot = atomicAdd(cursor + c, 1);
      intx2 rec = {r, __float_as_int(dist)};
      __builtin_nontemporal_store(rec, (intx2*)(recs + slot));
    }
    return;
  }

  // ---- gemm_proj: P1 = Eb@W1t^T, P2b = Eb@W2t^T + b_msg ----
  const int wv = threadIdx.x >> 6, lane = threadIdx.x & 63;
  const int q = lane >> 4, lr = lane & 15;
  const int m0 = blockIdx.x * 32;
  const int n0 = wv * 32;

  const ushort* Wt2[2] = {W1t, W2t};
  bf16x8 bfr[2][2][4];
#pragma unroll
  for (int ws = 0; ws < 2; ++ws)
#pragma unroll
    for (int nt = 0; nt < 2; ++nt) {
      int colc = n0 + nt * 16 + lr;
#pragma unroll
      for (int kc = 0; kc < 4; ++kc)
        bfr[ws][nt][kc] = load_frag(Wt2[ws] + colc * 128 + kc * 32 + q * 8);
    }

  floatx4 z = {0.f, 0.f, 0.f, 0.f};
  floatx4 acc[2][2][2];
#pragma unroll
  for (int ws = 0; ws < 2; ++ws)
#pragma unroll
    for (int mt = 0; mt < 2; ++mt)
#pragma unroll
      for (int nt = 0; nt < 2; ++nt) acc[ws][mt][nt] = z;

  const int r0 = min(m0 + lr, M - 1);
  const int r1 = min(m0 + 16 + lr, M - 1);
#pragma unroll
  for (int kc = 0; kc < 4; ++kc) {
    bf16x8 a0 = load_frag(Ab + (size_t)r0 * 128 + kc * 32 + q * 8);
    bf16x8 a1 = load_frag(Ab + (size_t)r1 * 128 + kc * 32 + q * 8);
#pragma unroll
    for (int ws = 0; ws < 2; ++ws)
#pragma unroll
      for (int nt = 0; nt < 2; ++nt) {
        acc[ws][0][nt] = __builtin_amdgcn_mfma_f32_16x16x32_bf16(a0, bfr[ws][nt][kc], acc[ws][0][nt], 0, 0, 0);
        acc[ws][1][nt] = __builtin_amdgcn_mfma_f32_16x16x32_bf16(a1, bfr[ws][nt][kc], acc[ws][1][nt], 0, 0, 0);
      }
  }

  ushort* Cp[2] = {P1, P2b};
#pragma unroll
  for (int ws = 0; ws < 2; ++ws)
#pragma unroll
    for (int nt = 0; nt < 2; ++nt) {
      int colc = n0 + nt * 16 + lr;
      float bias = (ws == 1) ? b_msg[colc] : 0.f;
#pragma unroll
      for (int mt = 0; mt < 2; ++mt)
#pragma unroll
        for (int i = 0; i < 4; ++i) {
          int r = m0 + mt * 16 + q * 4 + i;
          if (r < M) Cp[ws][(size_t)r * 128 + colc] = f2bf(acc[ws][mt][nt][i] + bias);
        }
    }
}

// ---- K4: aggregate — one wave per node, lane owns 2 channels, unroll 4 ----
__global__ __launch_bounds__(256) void aggregate(const int* __restrict__ offsets,
                                                 const int2* __restrict__ recs,
                                                 const ushort* __restrict__ P1,
                                                 const ushort* __restrict__ P2b,
                                                 const float* __restrict__ wd,
                                                 ushort* __restrict__ aggr, int M)
{
  int n = blockIdx.x * 4 + (threadIdx.x >> 6);
  if (n >= M) return;
  const int lane = threadIdx.x & 63;
  const int ch = lane * 2;

  float2 w = *(const float2*)(wd + ch);
  uint p2u = *(const uint*)(P2b + (size_t)n * 128 + ch);
  float p2x = bf2f(p2u & 0xffffu), p2y = bf2f(p2u >> 16);

  int i   = offsets[n];
  int end = offsets[n + 1];
  float a0 = 0.f, a1 = 0.f;

  auto edge = [&](int row, int di) {
    float d = __int_as_float(di);
    uint qu = *(const uint*)(P1 + (size_t)row * 128 + ch);
    a0 += fmaxf(fmaf(d, w.x, bf2f(qu & 0xffffu) + p2x), 0.f);
    a1 += fmaxf(fmaf(d, w.y, bf2f(qu >> 16)     + p2y), 0.f);
  };

  // peel to 16B alignment for intx4 (2-rec) NT loads
  if (i < end && (i & 1)) { int2 e0 = recs[i]; edge(e0.x, e0.y); ++i; }
  for (; i + 4 <= end; i += 4) {
    intx4 ra = __builtin_nontemporal_load((const intx4*)(recs + i));
    intx4 rb = __builtin_nontemporal_load((const intx4*)(recs + i + 2));
    edge(ra.x, ra.y); edge(ra.z, ra.w);
    edge(rb.x, rb.y); edge(rb.z, rb.w);
  }
  for (; i < end; ++i) { int2 e0 = recs[i]; edge(e0.x, e0.y); }

  uint o = (uint)f2bf(a0) | ((uint)f2bf(a1) << 16);
  __builtin_nontemporal_store(o, (uint*)(aggr + (size_t)n * 128 + ch));
}

// ---- K5: out = Eb@Wrt^T + relu(Eb@Wu1t^T + Gb@Wu2t^T + b_upd) ----
__global__ __launch_bounds__(256) void gemm_upd_mfma(
    const ushort* __restrict__ Eb, const ushort* __restrict__ Gb, int M,
    const ushort* __restrict__ Wu1t, const ushort* __restrict__ Wu2t,
    const ushort* __restrict__ Wrt, const float* __restrict__ b_upd,
    float* __restrict__ out)
{
  const int wv = threadIdx.x >> 6, lane = threadIdx.x & 63;
  const int q = lane >> 4, lr = lane & 15;
  const int m0 = blockIdx.x * 32;
  const int n0 = wv * 32;

  bf16x8 b1[2][4], b2[2][4], br[2][4];
#pragma unroll
  for (int nt = 0; nt < 2; ++nt) {
    int colc = n0 + nt * 16 + lr;
#pragma unroll
    for (int kc = 0; kc < 4; ++kc) {
      b1[nt][kc] = load_frag(Wu1t + colc * 128 + kc * 32 + q * 8);
      b2[nt][kc] = load_frag(Wu2t + colc * 128 + kc * 32 + q * 8);
      br[nt][kc] = load_frag(Wrt  + colc * 128 + kc * 32 + q * 8);
    }
  }

  floatx4 z = {0.f, 0.f, 0.f, 0.f};
  floatx4 acc_u[2][2], acc_r[2][2];
#pragma unroll
  for (int mt = 0; mt < 2; ++mt)
#pragma unroll
    for (int nt = 0; nt < 2; ++nt) { acc_u[mt][nt] = z; acc_r[mt][nt] = z; }

  const int r0 = min(m0 + lr, M - 1);
  const int r1 = min(m0 + 16 + lr, M - 1);
#pragma unroll
  for (int kc = 0; kc < 4; ++kc) {
    bf16x8 ae0 = load_frag(Eb + (size_t)r0 * 128 + kc * 32 + q * 8);
    bf16x8 ae1 = load_frag(Eb + (size_t)r1 * 128 + kc * 32 + q * 8);
    bf16x8 ag0 = load_frag(Gb + (size_t)r0 * 128 + kc * 32 + q * 8);
    bf16x8 ag1 = load_frag(Gb + (size_t)r1 * 128 + kc * 32 + q * 8);
#pragma unroll
    for (int nt = 0; nt < 2; ++nt) {
      acc_u[0][nt] = __builtin_amdgcn_mfma_f32_16x16x32_bf16(ae0, b1[nt][kc], acc_u[0][nt], 0, 0, 0);
      acc_u[1][nt] = __builtin_amdgcn_mfma_f32_16x16x32_bf16(ae1, b1[nt][kc], acc_u[1][nt], 0, 0, 0);
      acc_u[0][nt] = __builtin_amdgcn_mfma_f32_16x16x32_bf16(ag0, b2[nt][kc], acc_u[0][nt], 0, 0, 0);
      acc_u[1][nt] = __builtin_amdgcn_mfma_f32_16x16x32_bf16(ag1, b2[nt][kc], acc_u[1][nt], 0, 0, 0);
      acc_r[0][nt] = __builtin_amdgcn_mfma_f32_16x16x32_bf16(ae0, br[nt][kc], acc_r[0][nt], 0, 0, 0);
      acc_r[1][nt] = __builtin_amdgcn_mfma_f32_16x16x32_bf16(ae1, br[nt][kc], acc_r[1][nt], 0, 0, 0);
    }
  }

#pragma unroll
  for (int nt = 0; nt < 2; ++nt) {
    int colc = n0 + nt * 16 + lr;
    float bias = b_upd[colc];
#pragma unroll
    for (int mt = 0; mt < 2; ++mt)
#pragma unroll
      for (int i = 0; i < 4; ++i) {
        int r = m0 + mt * 16 + q * 4 + i;
        if (r < M)
          out[(size_t)r * 128 + colc] = acc_r[mt][nt][i] + fmaxf(acc_u[mt][nt][i] + bias, 0.f);
      }
  }
}

extern "C" void kernel_launch(void* const* d_in, const int* in_sizes, int n_in,
                              void* d_out, int out_size, void* d_ws, size_t ws_size,
                              hipStream_t stream)
{
  const float* embed = (const float*)d_in[0];
  const float* pos   = (const float*)d_in[1];
  const int*   ei    = (const int*)d_in[2];
  const float* W_res = (const float*)d_in[3];
  const float* W_msg = (const float*)d_in[4];
  const float* b_msg = (const float*)d_in[5];
  const float* W_upd = (const float*)d_in[6];
  const float* b_upd = (const float*)d_in[7];
  float* out = (float*)d_out;

  const int M = in_sizes[0] / 128;   // 50000
  const int E = in_sizes[2] / 2;     // 1.6M

  // Workspace (~65 MB)
  ushort* Eb   = (ushort*)d_ws;               // M*128 bf16
  ushort* P1b  = Eb  + (size_t)M * 128;
  ushort* P2b  = P1b + (size_t)M * 128;
  ushort* Gb   = P2b + (size_t)M * 128;
  ushort* Wt   = Gb  + (size_t)M * 128;       // 5 x 128x128 bf16 (transposed)
  int2*   recs = (int2*)(Wt + 5 * 16384);     // E
  int*   counts  = (int*)(recs + E);          // M
  int*   offsets = counts + M;                // M+1 (+pad)

  (void)hipMemsetAsync(counts, 0, (size_t)M * sizeof(int), stream);

  WSrc wsrc;
  wsrc.s[0] = W_msg;               // W1
  wsrc.s[1] = W_msg + 128 * 128;   // W2
  wsrc.s[2] = W_res;               // Wres
  wsrc.s[3] = W_upd;               // Wu1
  wsrc.s[4] = W_upd + 128 * 128;   // Wu2

  int n4 = M * 128 / 4;
  int nb_main = (max(n4, E) + 255) / 256;
  k1_cast_hist<<<nb_main + 5, 256, 0, stream>>>(embed, Eb, n4, ei + E, E, counts,
                                                wsrc, Wt, nb_main);

  scan_kernel<<<1, 1024, 0, stream>>>(counts, offsets, M);

  int rt = (M + 31) / 32;
  int sb = (E + 1023) / 1024;   // scatter blocks (4 edges/thread)
  k3_proj_scatter<<<rt + sb, 256, 0, stream>>>(Eb, M, rt, Wt, Wt + 16384, b_msg,
                                               P1b, P2b, ei, E, pos, counts, recs);

  aggregate<<<(M + 3) / 4, 256, 0, stream>>>(offsets, recs, P1b, P2b,
                                             W_msg + 256 * 128, Gb, M);

  gemm_upd_mfma<<<rt, 256, 0, stream>>>(Eb, Gb, M, Wt + 3 * 16384, Wt + 4 * 16384,
                                        Wt + 2 * 16384, b_upd, out);
}

// Round 6
// 398.519 us; speedup vs baseline: 3.8737x; 1.0251x over previous
//
#include <hip/hip_runtime.h>
#include <hip/hip_bf16.h>
#include <cstdint>

// EquivariantMPLayer restructured:
//   out = embed@W_res + relu(embed@Wu1 + aggr@Wu2 + b_upd)
//   aggr[c] = sum_{e: col[e]==c} relu(P1[row_e] + P2b[c] + dist_e*w_d)
//   P1 = embed@W1, P2b = embed@W2 + b_msg   (W_msg distributed over concat)
// Round 6: 4-byte packed edge records (row<<16 | bf16(dist), valid since
// N_NODES < 2^16), cacheable scatter stores (NT-on-random-scatter caused 64B/8B
// write amplification in R5), independent batched slot atomics, packed-f32
// (v_pk_*) math in aggregate, uintx4 NT rec streaming.

typedef __bf16 bf16x8 __attribute__((ext_vector_type(8)));
typedef float floatx4 __attribute__((ext_vector_type(4)));
typedef float floatx2 __attribute__((ext_vector_type(2)));
typedef unsigned int uintx4 __attribute__((ext_vector_type(4)));

__device__ __forceinline__ ushort f2bf(float f) {
  union { float f; uint i; } v; v.f = f;
  uint r = v.i + 0x7fff + ((v.i >> 16) & 1);   // RNE
  return (ushort)(r >> 16);
}
__device__ __forceinline__ bf16x8 load_frag(const ushort* p) {
  uint4 v = *(const uint4*)p;
  return __builtin_bit_cast(bf16x8, v);
}
__device__ __forceinline__ floatx2 pmax0(floatx2 a) {
#if __has_builtin(__builtin_elementwise_max)
  return __builtin_elementwise_max(a, (floatx2)(0.f));
#else
  floatx2 r; r.x = fmaxf(a.x, 0.f); r.y = fmaxf(a.y, 0.f); return r;
#endif
}

struct WSrc { const float* s[5]; };

// ---- K1: cast embed to bf16 + histogram of edge targets + weight transpose-cast ----
__global__ __launch_bounds__(256) void k1_cast_hist(
    const float* __restrict__ embed, ushort* __restrict__ Eb, int n4,
    const int* __restrict__ col, int E, int* __restrict__ counts,
    WSrc ws, ushort* __restrict__ Wt, int nb_main)
{
  if ((int)blockIdx.x >= nb_main) {
    int wb = blockIdx.x - nb_main;
    const float* s = ws.s[wb];
    ushort* d = Wt + wb * 16384;
    for (int i = threadIdx.x; i < 16384; i += 256) {
      int k = i >> 7, n = i & 127;
      d[n * 128 + k] = f2bf(s[i]);
    }
    return;
  }
  int i = blockIdx.x * 256 + threadIdx.x;
  if (i < n4) {
    float4 v = ((const float4*)embed)[i];
    ushort4 o;
    o.x = f2bf(v.x); o.y = f2bf(v.y); o.z = f2bf(v.z); o.w = f2bf(v.w);
    ((ushort4*)Eb)[i] = o;
  }
  if (i < E) atomicAdd(counts + col[i], 1);
}

// ---- K2: exclusive scan (int4-vectorized, 4096 elems/tile) ----
__global__ __launch_bounds__(1024) void scan_kernel(int* __restrict__ counts,
                                                    int* __restrict__ offsets, int n)
{
  __shared__ int wsum[16];
  __shared__ int wpre[16];
  __shared__ int s_carry, s_total;
  const int t = threadIdx.x;
  const int lane = t & 63, wid = t >> 6;
  if (t == 0) s_carry = 0;
  __syncthreads();

  const int n4 = (n + 3) >> 2;
  for (int b4 = 0; b4 < n4; b4 += 1024) {
    int i4 = b4 + t;
    int base = i4 * 4;
    int4 v = make_int4(0, 0, 0, 0);
    if (base + 3 < n) v = ((const int4*)counts)[i4];
    else if (base < n) {
      v.x = counts[base];
      if (base + 1 < n) v.y = counts[base + 1];
      if (base + 2 < n) v.z = counts[base + 2];
    }
    int tsum = v.x + v.y + v.z + v.w;
    int incl = tsum;
#pragma unroll
    for (int d = 1; d < 64; d <<= 1) {
      int u = __shfl_up(incl, d, 64);
      if (lane >= d) incl += u;
    }
    if (lane == 63) wsum[wid] = incl;
    __syncthreads();
    if (t == 0) {
      int run = 0;
#pragma unroll
      for (int j = 0; j < 16; ++j) { int x = wsum[j]; wpre[j] = run; run += x; }
      s_total = run;
    }
    __syncthreads();
    int excl = s_carry + wpre[wid] + incl - tsum;
    if (base + 3 < n) {
      int4 o;
      o.x = excl; o.y = o.x + v.x; o.z = o.y + v.y; o.w = o.z + v.z;
      ((int4*)offsets)[i4] = o;
      ((int4*)counts)[i4] = o;
    } else if (base < n) {
      int run = excl;
      offsets[base] = run; counts[base] = run; run += v.x;
      if (base + 1 < n) { offsets[base + 1] = run; counts[base + 1] = run; run += v.y; }
      if (base + 2 < n) { offsets[base + 2] = run; counts[base + 2] = run; }
    }
    __syncthreads();
    if (t == 0) s_carry += s_total;
    __syncthreads();
  }
  if (t == 0) offsets[n] = s_carry;
}

// ---- K3: gemm_proj (MFMA) + scatter, fused via blockIdx split ----
// MFMA 16x16x32 bf16 fragment layouts (verified m89/m120):
//   A: lane l, j -> A[m=l&15][k=(l>>4)*8+j];  B: lane l, j -> B[k=(l>>4)*8+j][n=l&15]
//   D: lane l, i -> D[m=(l>>4)*4+i][n=l&15]
__global__ __launch_bounds__(256) void k3_proj_scatter(
    const ushort* __restrict__ Ab, int M, int rt,
    const ushort* __restrict__ W1t, const ushort* __restrict__ W2t,
    const float* __restrict__ b_msg,
    ushort* __restrict__ P1, ushort* __restrict__ P2b,
    const int* __restrict__ ei, int E, const float* __restrict__ pos,
    int* __restrict__ cursor, uint* __restrict__ recs)
{
  if ((int)blockIdx.x >= rt) {
    // ---- scatter: 4 edges/thread; independent atomics, then cached stores ----
    int e4 = (blockIdx.x - rt) * 256 + threadIdx.x;
    int e0 = e4 * 4;
    if (e0 >= E) return;
    int4 rv = ((const int4*)ei)[e4];
    int4 cv = ((const int4*)(ei + E))[e4];
    int rr[4] = {rv.x, rv.y, rv.z, rv.w};
    int cc[4] = {cv.x, cv.y, cv.z, cv.w};
    uint rec[4]; int slot[4]; bool val[4];
#pragma unroll
    for (int j = 0; j < 4; ++j) {
      val[j] = (e0 + j < E);
      int r = val[j] ? rr[j] : 0, c = val[j] ? cc[j] : 0;
      float dx = pos[3 * r + 0] - pos[3 * c + 0];
      float dy = pos[3 * r + 1] - pos[3 * c + 1];
      float dz = pos[3 * r + 2] - pos[3 * c + 2];
      float dist = dx * dx + dy * dy + dz * dz;
      rec[j] = ((uint)r << 16) | (uint)f2bf(dist);
      if (val[j]) slot[j] = atomicAdd(cursor + c, 1);
    }
#pragma unroll
    for (int j = 0; j < 4; ++j)
      if (val[j]) recs[slot[j]] = rec[j];
    return;
  }

  // ---- gemm_proj: P1 = Eb@W1t^T, P2b = Eb@W2t^T + b_msg ----
  const int wv = threadIdx.x >> 6, lane = threadIdx.x & 63;
  const int q = lane >> 4, lr = lane & 15;
  const int m0 = blockIdx.x * 32;
  const int n0 = wv * 32;

  const ushort* Wt2[2] = {W1t, W2t};
  bf16x8 bfr[2][2][4];
#pragma unroll
  for (int ws = 0; ws < 2; ++ws)
#pragma unroll
    for (int nt = 0; nt < 2; ++nt) {
      int colc = n0 + nt * 16 + lr;
#pragma unroll
      for (int kc = 0; kc < 4; ++kc)
        bfr[ws][nt][kc] = load_frag(Wt2[ws] + colc * 128 + kc * 32 + q * 8);
    }

  floatx4 z = {0.f, 0.f, 0.f, 0.f};
  floatx4 acc[2][2][2];
#pragma unroll
  for (int ws = 0; ws < 2; ++ws)
#pragma unroll
    for (int mt = 0; mt < 2; ++mt)
#pragma unroll
      for (int nt = 0; nt < 2; ++nt) acc[ws][mt][nt] = z;

  const int r0 = min(m0 + lr, M - 1);
  const int r1 = min(m0 + 16 + lr, M - 1);
#pragma unroll
  for (int kc = 0; kc < 4; ++kc) {
    bf16x8 a0 = load_frag(Ab + (size_t)r0 * 128 + kc * 32 + q * 8);
    bf16x8 a1 = load_frag(Ab + (size_t)r1 * 128 + kc * 32 + q * 8);
#pragma unroll
    for (int ws = 0; ws < 2; ++ws)
#pragma unroll
      for (int nt = 0; nt < 2; ++nt) {
        acc[ws][0][nt] = __builtin_amdgcn_mfma_f32_16x16x32_bf16(a0, bfr[ws][nt][kc], acc[ws][0][nt], 0, 0, 0);
        acc[ws][1][nt] = __builtin_amdgcn_mfma_f32_16x16x32_bf16(a1, bfr[ws][nt][kc], acc[ws][1][nt], 0, 0, 0);
      }
  }

  ushort* Cp[2] = {P1, P2b};
#pragma unroll
  for (int ws = 0; ws < 2; ++ws)
#pragma unroll
    for (int nt = 0; nt < 2; ++nt) {
      int colc = n0 + nt * 16 + lr;
      float bias = (ws == 1) ? b_msg[colc] : 0.f;
#pragma unroll
      for (int mt = 0; mt < 2; ++mt)
#pragma unroll
        for (int i = 0; i < 4; ++i) {
          int r = m0 + mt * 16 + q * 4 + i;
          if (r < M) Cp[ws][(size_t)r * 128 + colc] = f2bf(acc[ws][mt][nt][i] + bias);
        }
    }
}

// ---- K4: aggregate — one wave per node, lane owns 2 channels, packed f32 math ----
__global__ __launch_bounds__(256) void aggregate(const int* __restrict__ offsets,
                                                 const uint* __restrict__ recs,
                                                 const ushort* __restrict__ P1,
                                                 const ushort* __restrict__ P2b,
                                                 const float* __restrict__ wd,
                                                 ushort* __restrict__ aggr, int M)
{
  int n = blockIdx.x * 4 + (threadIdx.x >> 6);
  if (n >= M) return;
  const int lane = threadIdx.x & 63;
  const int ch = lane * 2;

  float2 wl = *(const float2*)(wd + ch);
  floatx2 wv = {wl.x, wl.y};
  uint p2u = *(const uint*)(P2b + (size_t)n * 128 + ch);
  floatx2 p2 = {__int_as_float((int)(p2u << 16)),
                __int_as_float((int)(p2u & 0xffff0000u))};

  int i   = offsets[n];
  int end = offsets[n + 1];
  floatx2 acc = {0.f, 0.f};

  auto edge = [&](uint rec) {
    float d = __int_as_float((int)(rec << 16));      // bf16 dist in low 16
    uint row = rec >> 16;
    uint qu = *(const uint*)(P1 + (size_t)row * 128 + ch);
    floatx2 qv = {__int_as_float((int)(qu << 16)),
                  __int_as_float((int)(qu & 0xffff0000u))};
    floatx2 base = qv + p2;
#if __has_builtin(__builtin_elementwise_fma)
    floatx2 t = __builtin_elementwise_fma((floatx2)(d), wv, base);
#else
    floatx2 t = (floatx2)(d) * wv + base;
#endif
    acc += pmax0(t);
  };

  // peel to 16B alignment for uintx4 (4-rec) NT loads
  while (i < end && (i & 3)) { edge(recs[i]); ++i; }
  for (; i + 4 <= end; i += 4) {
    uintx4 rv = __builtin_nontemporal_load((const uintx4*)(recs + i));
    edge(rv.x); edge(rv.y); edge(rv.z); edge(rv.w);
  }
  for (; i < end; ++i) edge(recs[i]);

  uint o = (uint)f2bf(acc.x) | ((uint)f2bf(acc.y) << 16);
  *(uint*)(aggr + (size_t)n * 128 + ch) = o;   // cacheable: gemm_upd reads it next
}

// ---- K5: out = Eb@Wrt^T + relu(Eb@Wu1t^T + Gb@Wu2t^T + b_upd) ----
__global__ __launch_bounds__(256) void gemm_upd_mfma(
    const ushort* __restrict__ Eb, const ushort* __restrict__ Gb, int M,
    const ushort* __restrict__ Wu1t, const ushort* __restrict__ Wu2t,
    const ushort* __restrict__ Wrt, const float* __restrict__ b_upd,
    float* __restrict__ out)
{
  const int wv = threadIdx.x >> 6, lane = threadIdx.x & 63;
  const int q = lane >> 4, lr = lane & 15;
  const int m0 = blockIdx.x * 32;
  const int n0 = wv * 32;

  bf16x8 b1[2][4], b2[2][4], br[2][4];
#pragma unroll
  for (int nt = 0; nt < 2; ++nt) {
    int colc = n0 + nt * 16 + lr;
#pragma unroll
    for (int kc = 0; kc < 4; ++kc) {
      b1[nt][kc] = load_frag(Wu1t + colc * 128 + kc * 32 + q * 8);
      b2[nt][kc] = load_frag(Wu2t + colc * 128 + kc * 32 + q * 8);
      br[nt][kc] = load_frag(Wrt  + colc * 128 + kc * 32 + q * 8);
    }
  }

  floatx4 z = {0.f, 0.f, 0.f, 0.f};
  floatx4 acc_u[2][2], acc_r[2][2];
#pragma unroll
  for (int mt = 0; mt < 2; ++mt)
#pragma unroll
    for (int nt = 0; nt < 2; ++nt) { acc_u[mt][nt] = z; acc_r[mt][nt] = z; }

  const int r0 = min(m0 + lr, M - 1);
  const int r1 = min(m0 + 16 + lr, M - 1);
#pragma unroll
  for (int kc = 0; kc < 4; ++kc) {
    bf16x8 ae0 = load_frag(Eb + (size_t)r0 * 128 + kc * 32 + q * 8);
    bf16x8 ae1 = load_frag(Eb + (size_t)r1 * 128 + kc * 32 + q * 8);
    bf16x8 ag0 = load_frag(Gb + (size_t)r0 * 128 + kc * 32 + q * 8);
    bf16x8 ag1 = load_frag(Gb + (size_t)r1 * 128 + kc * 32 + q * 8);
#pragma unroll
    for (int nt = 0; nt < 2; ++nt) {
      acc_u[0][nt] = __builtin_amdgcn_mfma_f32_16x16x32_bf16(ae0, b1[nt][kc], acc_u[0][nt], 0, 0, 0);
      acc_u[1][nt] = __builtin_amdgcn_mfma_f32_16x16x32_bf16(ae1, b1[nt][kc], acc_u[1][nt], 0, 0, 0);
      acc_u[0][nt] = __builtin_amdgcn_mfma_f32_16x16x32_bf16(ag0, b2[nt][kc], acc_u[0][nt], 0, 0, 0);
      acc_u[1][nt] = __builtin_amdgcn_mfma_f32_16x16x32_bf16(ag1, b2[nt][kc], acc_u[1][nt], 0, 0, 0);
      acc_r[0][nt] = __builtin_amdgcn_mfma_f32_16x16x32_bf16(ae0, br[nt][kc], acc_r[0][nt], 0, 0, 0);
      acc_r[1][nt] = __builtin_amdgcn_mfma_f32_16x16x32_bf16(ae1, br[nt][kc], acc_r[1][nt], 0, 0, 0);
    }
  }

#pragma unroll
  for (int nt = 0; nt < 2; ++nt) {
    int colc = n0 + nt * 16 + lr;
    float bias = b_upd[colc];
#pragma unroll
    for (int mt = 0; mt < 2; ++mt)
#pragma unroll
      for (int i = 0; i < 4; ++i) {
        int r = m0 + mt * 16 + q * 4 + i;
        if (r < M)
          out[(size_t)r * 128 + colc] = acc_r[mt][nt][i] + fmaxf(acc_u[mt][nt][i] + bias, 0.f);
      }
  }
}

extern "C" void kernel_launch(void* const* d_in, const int* in_sizes, int n_in,
                              void* d_out, int out_size, void* d_ws, size_t ws_size,
                              hipStream_t stream)
{
  const float* embed = (const float*)d_in[0];
  const float* pos   = (const float*)d_in[1];
  const int*   ei    = (const int*)d_in[2];
  const float* W_res = (const float*)d_in[3];
  const float* W_msg = (const float*)d_in[4];
  const float* b_msg = (const float*)d_in[5];
  const float* W_upd = (const float*)d_in[6];
  const float* b_upd = (const float*)d_in[7];
  float* out = (float*)d_out;

  const int M = in_sizes[0] / 128;   // 50000 (< 2^16, required for packed recs)
  const int E = in_sizes[2] / 2;     // 1.6M

  // Workspace (~58 MB)
  ushort* Eb   = (ushort*)d_ws;               // M*128 bf16
  ushort* P1b  = Eb  + (size_t)M * 128;
  ushort* P2b  = P1b + (size_t)M * 128;
  ushort* Gb   = P2b + (size_t)M * 128;
  ushort* Wt   = Gb  + (size_t)M * 128;       // 5 x 128x128 bf16 (transposed)
  uint*   recs = (uint*)(Wt + 5 * 16384);     // E packed {row:16, bf16dist:16}
  int*   counts  = (int*)(recs + E);          // M
  int*   offsets = counts + M;                // M+1

  (void)hipMemsetAsync(counts, 0, (size_t)M * sizeof(int), stream);

  WSrc wsrc;
  wsrc.s[0] = W_msg;               // W1
  wsrc.s[1] = W_msg + 128 * 128;   // W2
  wsrc.s[2] = W_res;               // Wres
  wsrc.s[3] = W_upd;               // Wu1
  wsrc.s[4] = W_upd + 128 * 128;   // Wu2

  int n4 = M * 128 / 4;
  int nb_main = (max(n4, E) + 255) / 256;
  k1_cast_hist<<<nb_main + 5, 256, 0, stream>>>(embed, Eb, n4, ei + E, E, counts,
                                                wsrc, Wt, nb_main);

  scan_kernel<<<1, 1024, 0, stream>>>(counts, offsets, M);

  int rt = (M + 31) / 32;
  int sb = (E + 1023) / 1024;   // scatter blocks (4 edges/thread)
  k3_proj_scatter<<<rt + sb, 256, 0, stream>>>(Eb, M, rt, Wt, Wt + 16384, b_msg,
                                               P1b, P2b, ei, E, pos, counts, recs);

  aggregate<<<(M + 3) / 4, 256, 0, stream>>>(offsets, recs, P1b, P2b,
                                             W_msg + 256 * 128, Gb, M);

  gemm_upd_mfma<<<rt, 256, 0, stream>>>(Eb, Gb, M, Wt + 3 * 16384, Wt + 4 * 16384,
                                        Wt + 2 * 16384, b_upd, out);
}